// Round 2
// baseline (4604.348 us; speedup 1.0000x reference)
//
#include <hip/hip_runtime.h>

// ---------------------------------------------------------------------------
// RMT layer: B=16 chains x NM=64 sequential steps.
// Round 2: x-row K/V hoisted into one big upfront MFMA GEMM (all 64 steps);
// per-step = 3 kernels: k_step1 (QKV-mem + RoPE + attention fused),
// k_gemm2 (enc@wo), k_ln2. GEMMs use global_load_lds(16B) with a swizzled
// lane->(row,kchunk) staging map so ds_read_b128 fragment reads are
// conflict-free. All math bit-identical to round 1 (absmax 0.078125).
// ---------------------------------------------------------------------------

typedef __attribute__((ext_vector_type(8))) _Float16 f16x8;
typedef __attribute__((ext_vector_type(4))) _Float16 f16x4;
typedef __attribute__((ext_vector_type(8))) short    s16x8;
typedef __attribute__((ext_vector_type(4))) float    f32x4;

#define NB   16
#define NMs  64
#define MBs  64
#define Dm   1024
#define NHh  16
#define NKVh 8
#define HDd  64
#define MEMm 64

// ---------------- static device scratch ------------------------------------
__device__ __align__(16) _Float16      g_W1t[2048 * 1024];   // [n][k]: 0..1023 q, 1024..1535 k, 1536..2047 v
__device__ __align__(16) _Float16      g_Wot[1024 * 1024];   // wo^T [n][k]
__device__ __align__(16) float         g_rc[128 * 32];
__device__ __align__(16) float         g_rs[128 * 32];
__device__                unsigned char g_mask[NB * NMs];
__device__ __align__(16) _Float16      g_hx[(size_t)NB * NMs * MBs * Dm]; // LN'd x rows, f16
__device__ __align__(16) _Float16      g_hmem[NB * MEMm * Dm];            // LN'd mem rows, f16
__device__ __align__(16) float         g_memA[NB * MEMm * Dm];
__device__ __align__(16) float         g_memB[NB * MEMm * Dm];
// hoisted x-row K/V for all steps: [s][b][kvh][pos0..63][d]  bf16 (67 MB each)
__device__ __align__(16) unsigned short g_kx[(size_t)NMs * NB * NKVh * 64 * 64];
__device__ __align__(16) unsigned short g_vx[(size_t)NMs * NB * NKVh * 64 * 64];
__device__ __align__(16) _Float16      g_enc[NB * 64 * Dm];           // attention out, f16
__device__ __align__(16) float         g_outp[NB * 64 * Dm];          // enc @ wo, fp32

// ---------------- helpers ---------------------------------------------------
__device__ __forceinline__ unsigned short f2bf(float x) {
    union { float f; unsigned u; } v; v.f = x;
    unsigned u = v.u;
    return (unsigned short)((u + 0x7fffu + ((u >> 16) & 1u)) >> 16);  // RNE
}
__device__ __forceinline__ float bf2f(unsigned short h) {
    union { unsigned u; float f; } v; v.u = ((unsigned)h) << 16; return v.f;
}

__device__ __forceinline__ void gload_lds16(const void* g, void* l) {
    __builtin_amdgcn_global_load_lds(
        (const __attribute__((address_space(1))) unsigned int*)g,
        (__attribute__((address_space(3))) unsigned int*)l, 16, 0, 0);
}

// block-wide (256 thr) mean/rstd from per-thread partial sums
__device__ __forceinline__ void block_stats(float s, float ss, float eps,
                                            float* mean, float* rstd) {
    for (int off = 32; off > 0; off >>= 1) {
        s  += __shfl_down(s, off);
        ss += __shfl_down(ss, off);
    }
    __shared__ float red[8];
    int wid = threadIdx.x >> 6, lane = threadIdx.x & 63;
    __syncthreads();
    if (lane == 0) { red[wid] = s; red[4 + wid] = ss; }
    __syncthreads();
    float ts  = red[0] + red[1] + red[2] + red[3];
    float tss = red[4] + red[5] + red[6] + red[7];
    float m   = ts * (1.0f / 1024.0f);
    float var = tss * (1.0f / 1024.0f) - m * m;
    *mean = m;
    *rstd = rsqrtf(var + eps);
}

// ---------------- init kernels ----------------------------------------------
__global__ void k_transpose(const float* __restrict__ in, int ncols, int dsel) {
    _Float16* out = (dsel == 0) ? g_W1t
                  : (dsel == 1) ? (g_W1t + 1024 * 1024)
                  : (dsel == 2) ? (g_W1t + 1536 * 1024)
                                : g_Wot;
    __shared__ float tile[64][65];
    int bk = blockIdx.x, bn = blockIdx.y;
    int c = threadIdx.x & 63, rg = threadIdx.x >> 6;
    int k0 = bk * 64, n0 = bn * 64;
    for (int i = 0; i < 16; i++) {
        int r = rg * 16 + i;
        tile[r][c] = in[(size_t)(k0 + r) * ncols + n0 + c];
    }
    __syncthreads();
    for (int i = 0; i < 16; i++) {
        int r = rg * 16 + i;
        out[(size_t)(n0 + r) * 1024 + k0 + c] = (_Float16)tile[c][r];
    }
}

__global__ void k_rope() {
    int t = threadIdx.x;  // 128 positions
    for (int j = 0; j < 32; j++) {
        double f = pow(10000.0, -(double)j / 32.0);
        double a = (double)t * f;
        g_rc[t * 32 + j] = (float)cos(a);
        g_rs[t * 32 + j] = (float)sin(a);
    }
}

__global__ void k_mask(const unsigned int* __restrict__ ip) {
    __shared__ int byteFmt;
    int t = threadIdx.x;  // 1024
    if (t == 0) byteFmt = 0;
    __syncthreads();
    if (t < 256) {
        unsigned v = ip[t];
        if (!(v == 0u || v == 1u || v == 0x3F800000u)) byteFmt = 1;
    }
    __syncthreads();
    unsigned char m = byteFmt ? (((const unsigned char*)ip)[t] != 0)
                              : (ip[t] != 0u);
    g_mask[t] = m;
}

__global__ void k_ln_hx(const float* __restrict__ x,
                        const float* __restrict__ sc, const float* __restrict__ bi) {
    size_t row = blockIdx.x;
    int t = threadIdx.x;
    float4 v = ((const float4*)(x + row * 1024))[t];
    float mean, rstd;
    block_stats(v.x + v.y + v.z + v.w,
                v.x * v.x + v.y * v.y + v.z * v.z + v.w * v.w, 1e-6f, &mean, &rstd);
    float4 s4 = ((const float4*)sc)[t];
    float4 b4 = ((const float4*)bi)[t];
    f16x4 o;
    o[0] = (_Float16)((v.x - mean) * rstd * s4.x + b4.x);
    o[1] = (_Float16)((v.y - mean) * rstd * s4.y + b4.y);
    o[2] = (_Float16)((v.z - mean) * rstd * s4.z + b4.z);
    o[3] = (_Float16)((v.w - mean) * rstd * s4.w + b4.w);
    *(f16x4*)(g_hx + row * 1024 + t * 4) = o;
}

__global__ void k_ln_init(const float* __restrict__ ms,
                          const float* __restrict__ sc, const float* __restrict__ bi) {
    int b = blockIdx.x >> 6, r = blockIdx.x & 63;
    int t = threadIdx.x;
    float4 v = ((const float4*)(ms + (size_t)r * 1024))[t];
    ((float4*)(g_memA + ((size_t)b * 64 + r) * 1024))[t] = v;
    float mean, rstd;
    block_stats(v.x + v.y + v.z + v.w,
                v.x * v.x + v.y * v.y + v.z * v.z + v.w * v.w, 1e-6f, &mean, &rstd);
    float4 s4 = ((const float4*)sc)[t];
    float4 b4 = ((const float4*)bi)[t];
    f16x4 o;
    o[0] = (_Float16)((v.x - mean) * rstd * s4.x + b4.x);
    o[1] = (_Float16)((v.y - mean) * rstd * s4.y + b4.y);
    o[2] = (_Float16)((v.z - mean) * rstd * s4.z + b4.z);
    o[3] = (_Float16)((v.w - mean) * rstd * s4.w + b4.w);
    *(f16x4*)(g_hmem + ((size_t)b * 64 + r) * 1024 + t * 4) = o;
}

// ---------------------------------------------------------------------------
// Hoisted x-row K/V GEMM: [65536 x 1024] (g_hx) @ [1024 kv-cols] (W1t rows
// 1024..2047, n-major). 128x128 tiles, BK=32, global_load_lds staging with
// lane map (row = l&15, kchunk = l>>4) -> LDS [rg][kc][row][8 f16]:
// fragment ds_read_b128 is then fully coalesced across fr lanes (16B stride).
// Epilogue: RoPE(k) + bf16 round -> LDS transpose -> vectorized scatter to
// g_kx/g_vx [s][b][kvh][pos][d]. Math identical to round-1 mtile0 path.
// ---------------------------------------------------------------------------
__launch_bounds__(256)
__global__ void k_kvx() {
    int tm = blockIdx.x, tn = blockIdx.y;        // 512 x 8
    int tid = threadIdx.x, w = tid >> 6, l = tid & 63;
    int fr = l & 15, kc = l >> 4;
    __shared__ __align__(16) _Float16 As[8 * 512];   // [rg(8)][kc(4)][fr(16)][8]
    __shared__ __align__(16) _Float16 Bs[8 * 512];
    __shared__ __align__(16) unsigned short Ct[128 * 132];
    const _Float16* A = g_hx + (size_t)tm * 128 * 1024;
    const _Float16* B = g_W1t + (size_t)(1024 + tn * 128) * 1024;
    int wm = w & 1, wn = w >> 1;
    f32x4 acc[4][4];
    #pragma unroll
    for (int i = 0; i < 4; i++)
        #pragma unroll
        for (int j = 0; j < 4; j++) acc[i][j] = (f32x4){0.f, 0.f, 0.f, 0.f};

    for (int kt = 0; kt < 32; ++kt) {
        #pragma unroll
        for (int jj = 0; jj < 2; ++jj) {
            int rg = w * 2 + jj;
            gload_lds16(A + (size_t)(rg * 16 + fr) * 1024 + kt * 32 + kc * 8,
                        (char*)As + rg * 1024);
            gload_lds16(B + (size_t)(rg * 16 + fr) * 1024 + kt * 32 + kc * 8,
                        (char*)Bs + rg * 1024);
        }
        __syncthreads();
        f16x8 af[4], bg[4];
        #pragma unroll
        for (int i = 0; i < 4; i++) {
            af[i] = *(const f16x8*)&As[(wm * 4 + i) * 512 + kc * 128 + fr * 8];
            bg[i] = *(const f16x8*)&Bs[(wn * 4 + i) * 512 + kc * 128 + fr * 8];
        }
        #pragma unroll
        for (int i = 0; i < 4; i++)
            #pragma unroll
            for (int j = 0; j < 4; j++)
                acc[i][j] = __builtin_amdgcn_mfma_f32_16x16x32_f16(af[i], bg[j], acc[i][j], 0, 0, 0);
        __syncthreads();
    }
    // epilogue: RoPE on k cols, bf16 round, LDS transpose
    int quad = kc;
    #pragma unroll
    for (int i = 0; i < 4; i++)
        #pragma unroll
        for (int j = 0; j < 4; j++)
            #pragma unroll
            for (int r = 0; r < 4; r++) {
                float val = acc[i][j][r];
                float p = __shfl_xor(val, 1);
                int rl = wm * 64 + i * 16 + quad * 4 + r;   // local row 0..127
                int cl = wn * 64 + j * 16 + fr;             // local col 0..127
                int c = tn * 128 + cl;                      // kv col 0..1023
                unsigned short ob;
                if (c < 512) {                              // k: RoPE
                    int d = c & 63, pos = rl & 63;
                    int j2 = d >> 1;
                    float cc = g_rc[pos * 32 + j2], sn = g_rs[pos * 32 + j2];
                    float o = (d & 1) ? (p * sn + val * cc) : (val * cc - p * sn);
                    ob = f2bf(o);
                } else {
                    ob = f2bf(val);
                }
                Ct[rl * 132 + cl] = ob;
            }
    __syncthreads();
    // vectorized scatter: thread -> (row, 64-col half)
    int row = tid >> 1, half = tid & 1;
    size_t R = (size_t)tm * 128 + row;
    int bb = (int)(R >> 12), ss = (int)((R >> 6) & 63), pos = (int)(R & 63);
    int cb = tn * 128 + half * 64;
    unsigned short* dst = (cb < 512)
        ? (g_kx + ((((size_t)ss * 16 + bb) * 8) + (cb >> 6)) * 4096 + pos * 64)
        : (g_vx + ((((size_t)ss * 16 + bb) * 8) + ((cb - 512) >> 6)) * 4096 + pos * 64);
    const ushort4* src = (const ushort4*)&Ct[row * 132 + half * 64];
    #pragma unroll
    for (int j = 0; j < 16; j++) ((ushort4*)dst)[j] = src[j];
}

// ---------------------------------------------------------------------------
// k_step1: per (b,h): GEMM h_mem[64x1024] @ W1t cols {q_h, k_kvh, v_kvh}
// (64x192, BK=64, B staged via global_load_lds, A direct frags), RoPE, bf16,
// then attention (QK^T 64x128, softmax, PV) entirely from LDS/registers.
// ---------------------------------------------------------------------------
__launch_bounds__(256)
__global__ void k_step1(int s) {
    int b = blockIdx.x >> 4, h = blockIdx.x & 15, kvh = h >> 1;
    int tid = threadIdx.x, w = tid >> 6, l = tid & 63;
    int fr = l & 15, kc = l >> 4, quad = kc;
    __shared__ __align__(16) _Float16       Bs[24 * 512];     // 24KB staged W1t cols
    __shared__ __align__(16) unsigned short q_s[64 * 72];     // q bf16 [row][d]
    __shared__ __align__(16) unsigned short k_s[64 * 72];     // k-mem bf16 [pos-64][d]
    __shared__ __align__(16) unsigned short vt_s[64 * 136];   // v^T bf16 [d][pos0..127]
    __shared__ __align__(16) unsigned short p_s[4][16 * 136]; // att bf16 per wave

    const _Float16* A = g_hmem + (size_t)b * 64 * 1024;

    // stage x-part of v^T (transpose g_vx [pos][d] -> vt_s [d][pos])
    {
        const unsigned short* vx = g_vx + (((size_t)s * 16 + b) * 8 + kvh) * 4096;
        int pos = tid & 63, dg = tid >> 6;
        const ushort2* src = (const ushort2*)(vx + pos * 64 + dg * 16);
        ushort2 tmp[8];
        #pragma unroll
        for (int j = 0; j < 8; j++) tmp[j] = src[j];
        #pragma unroll
        for (int j = 0; j < 8; j++) {
            vt_s[(dg * 16 + 2 * j)     * 136 + pos] = tmp[j].x;
            vt_s[(dg * 16 + 2 * j + 1) * 136 + pos] = tmp[j].y;
        }
    }

    // ---- GEMM 64x192, K=1024, BK=64 ----
    f32x4 acc[12];
    #pragma unroll
    for (int i = 0; i < 12; i++) acc[i] = (f32x4){0.f, 0.f, 0.f, 0.f};
    int browQ = h * 64, browK = 1024 + kvh * 64, browV = 1536 + kvh * 64;

    for (int kt = 0; kt < 16; ++kt) {
        #pragma unroll
        for (int jj = 0; jj < 6; ++jj) {
            int m = w * 6 + jj, rg = m % 12, khalf = m / 12;
            int r192 = rg * 16 + fr;
            int brow = (r192 < 64) ? (browQ + r192)
                     : (r192 < 128) ? (browK + r192 - 64)
                                    : (browV + r192 - 128);
            gload_lds16(g_W1t + (size_t)brow * 1024 + kt * 64 + khalf * 32 + kc * 8,
                        (char*)Bs + m * 1024);
        }
        f16x8 a0 = *(const f16x8*)(A + (size_t)(w * 16 + fr) * 1024 + kt * 64 + kc * 8);
        f16x8 a1 = *(const f16x8*)(A + (size_t)(w * 16 + fr) * 1024 + kt * 64 + 32 + kc * 8);
        __syncthreads();
        #pragma unroll
        for (int nt = 0; nt < 12; ++nt) {
            f16x8 b0 = *(const f16x8*)&Bs[nt * 512 + kc * 128 + fr * 8];
            f16x8 b1 = *(const f16x8*)&Bs[(12 + nt) * 512 + kc * 128 + fr * 8];
            acc[nt] = __builtin_amdgcn_mfma_f32_16x16x32_f16(a0, b0, acc[nt], 0, 0, 0);
            acc[nt] = __builtin_amdgcn_mfma_f32_16x16x32_f16(a1, b1, acc[nt], 0, 0, 0);
        }
        __syncthreads();
    }

    // ---- epilogue: RoPE + bf16 -> LDS (q_s, k_s, vt_s mem part) ----
    #pragma unroll
    for (int nt = 0; nt < 12; ++nt)
        #pragma unroll
        for (int r = 0; r < 4; ++r) {
            float val = acc[nt][r];
            float p = __shfl_xor(val, 1);
            int row = w * 16 + quad * 4 + r;   // mem index 0..63
            int col = nt * 16 + fr;            // 0..191
            if (col < 128) {                   // q or k: RoPE at pos=64+row
                int d = col & 63, pos = 64 + row;
                int j2 = d >> 1;
                float cc = g_rc[pos * 32 + j2], sn = g_rs[pos * 32 + j2];
                float o = (d & 1) ? (p * sn + val * cc) : (val * cc - p * sn);
                unsigned short bo = f2bf(o);
                if (col < 64) q_s[row * 72 + d] = bo;
                else          k_s[row * 72 + d] = bo;
            } else {
                int d = col - 128;
                vt_s[d * 136 + 64 + row] = f2bf(val);
            }
        }
    __syncthreads();

    // ---- QK^T: wave w handles q rows w*16..+15, all 128 positions ----
    s16x8 qa0 = *(const s16x8*)&q_s[(w * 16 + fr) * 72 + kc * 8];
    s16x8 qa1 = *(const s16x8*)&q_s[(w * 16 + fr) * 72 + 32 + kc * 8];
    const unsigned short* kx = g_kx + (((size_t)s * 16 + b) * 8 + kvh) * 4096;
    f32x4 sc[8];
    #pragma unroll
    for (int nt = 0; nt < 8; ++nt) {
        sc[nt] = (f32x4){0.f, 0.f, 0.f, 0.f};
        s16x8 kb0, kb1;
        if (nt < 4) {   // x part from global (positions 0..63)
            kb0 = *(const s16x8*)(kx + (nt * 16 + fr) * 64 + kc * 8);
            kb1 = *(const s16x8*)(kx + (nt * 16 + fr) * 64 + 32 + kc * 8);
        } else {        // mem part from LDS (positions 64..127)
            kb0 = *(const s16x8*)&k_s[((nt - 4) * 16 + fr) * 72 + kc * 8];
            kb1 = *(const s16x8*)&k_s[((nt - 4) * 16 + fr) * 72 + 32 + kc * 8];
        }
        sc[nt] = __builtin_amdgcn_mfma_f32_16x16x32_bf16(qa0, kb0, sc[nt], 0, 0, 0);
        sc[nt] = __builtin_amdgcn_mfma_f32_16x16x32_bf16(qa1, kb1, sc[nt], 0, 0, 0);
    }

    // ---- softmax (bf16-round logits, *scale, fp32 softmax, bf16 att) ----
    float lv[8][4];
    #pragma unroll
    for (int nt = 0; nt < 8; nt++)
        #pragma unroll
        for (int r = 0; r < 4; r++)
            lv[nt][r] = bf2f(f2bf(sc[nt][r])) * 0.125f;
    #pragma unroll
    for (int r = 0; r < 4; r++) {
        float mx = -1e30f;
        #pragma unroll
        for (int nt = 0; nt < 8; nt++) mx = fmaxf(mx, lv[nt][r]);
        for (int off = 1; off < 16; off <<= 1) mx = fmaxf(mx, __shfl_xor(mx, off));
        float sm = 0.f;
        #pragma unroll
        for (int nt = 0; nt < 8; nt++) { lv[nt][r] = expf(lv[nt][r] - mx); sm += lv[nt][r]; }
        for (int off = 1; off < 16; off <<= 1) sm += __shfl_xor(sm, off);
        float inv = 1.0f / sm;
        int row = quad * 4 + r;
        #pragma unroll
        for (int nt = 0; nt < 8; nt++)
            p_s[w][row * 136 + nt * 16 + fr] = f2bf(lv[nt][r] * inv);
    }
    __syncthreads();

    // ---- PV: att [16x128] @ v^T [d][pos] ----
    f32x4 o[4];
    #pragma unroll
    for (int nt = 0; nt < 4; nt++) o[nt] = (f32x4){0.f, 0.f, 0.f, 0.f};
    for (int kt2 = 0; kt2 < 4; ++kt2) {
        s16x8 pa = *(const s16x8*)&p_s[w][fr * 136 + kt2 * 32 + kc * 8];
        #pragma unroll
        for (int nt = 0; nt < 4; ++nt) {
            s16x8 vb = *(const s16x8*)&vt_s[(nt * 16 + fr) * 136 + kt2 * 32 + kc * 8];
            o[nt] = __builtin_amdgcn_mfma_f32_16x16x32_bf16(pa, vb, o[nt], 0, 0, 0);
        }
    }
    #pragma unroll
    for (int nt = 0; nt < 4; nt++)
        #pragma unroll
        for (int r = 0; r < 4; r++) {
            int m = w * 16 + quad * 4 + r;
            int d = nt * 16 + fr;
            g_enc[((size_t)b * 64 + m) * 1024 + h * 64 + d] =
                (_Float16)bf2f(f2bf(o[nt][r]));
        }
}

// ---------------------------------------------------------------------------
// k_gemm2: out = enc @ wo.  grid 256 = (b, ntile), BK=64, staged B.
// ---------------------------------------------------------------------------
__launch_bounds__(256)
__global__ void k_gemm2() {
    int b = blockIdx.x >> 4, nt4 = blockIdx.x & 15;
    int tid = threadIdx.x, w = tid >> 6, l = tid & 63;
    int fr = l & 15, kc = l >> 4, quad = kc;
    __shared__ __align__(16) _Float16 Bs[8 * 512];
    const _Float16* A = g_enc + (size_t)b * 64 * 1024;
    const _Float16* B = g_Wot + (size_t)nt4 * 64 * 1024;
    f32x4 acc[4];
    #pragma unroll
    for (int i = 0; i < 4; i++) acc[i] = (f32x4){0.f, 0.f, 0.f, 0.f};
    for (int kt = 0; kt < 16; ++kt) {
        #pragma unroll
        for (int jj = 0; jj < 2; ++jj) {
            int m = w * 2 + jj, rg = m & 3, khalf = m >> 2;
            gload_lds16(B + (size_t)(rg * 16 + fr) * 1024 + kt * 64 + khalf * 32 + kc * 8,
                        (char*)Bs + m * 1024);
        }
        f16x8 a0 = *(const f16x8*)(A + (size_t)(w * 16 + fr) * 1024 + kt * 64 + kc * 8);
        f16x8 a1 = *(const f16x8*)(A + (size_t)(w * 16 + fr) * 1024 + kt * 64 + 32 + kc * 8);
        __syncthreads();
        #pragma unroll
        for (int nt = 0; nt < 4; ++nt) {
            f16x8 b0 = *(const f16x8*)&Bs[nt * 512 + kc * 128 + fr * 8];
            f16x8 b1 = *(const f16x8*)&Bs[(4 + nt) * 512 + kc * 128 + fr * 8];
            acc[nt] = __builtin_amdgcn_mfma_f32_16x16x32_f16(a0, b0, acc[nt], 0, 0, 0);
            acc[nt] = __builtin_amdgcn_mfma_f32_16x16x32_f16(a1, b1, acc[nt], 0, 0, 0);
        }
        __syncthreads();
    }
    #pragma unroll
    for (int nt = 0; nt < 4; nt++)
        #pragma unroll
        for (int r = 0; r < 4; r++)
            g_outp[((size_t)b * 64 + w * 16 + quad * 4 + r) * 1024 + nt4 * 64 + nt * 16 + fr]
                = acc[nt][r];
}

// new_mem = LN_post(out+mem), masked select; also h_mem = LN_pre(new_mem). grid=1024
__global__ void k_ln2(int s, float* __restrict__ dout,
                      const float* __restrict__ psc, const float* __restrict__ pbi,
                      const float* __restrict__ qsc, const float* __restrict__ qbi) {
    int b = blockIdx.x >> 6, r = blockIdx.x & 63;
    const float* memIn = (s & 1) ? g_memB : g_memA;
    float* memOut = (s == 63) ? dout : ((s & 1) ? g_memA : g_memB);
    int t = threadIdx.x;
    size_t row = (size_t)b * 64 + r;
    float4 ov = ((const float4*)(g_outp + row * 1024))[t];
    float4 mv = ((const float4*)(memIn + row * 1024))[t];
    float4 y = {ov.x + mv.x, ov.y + mv.y, ov.z + mv.z, ov.w + mv.w};
    float mean, rstd;
    block_stats(y.x + y.y + y.z + y.w,
                y.x * y.x + y.y * y.y + y.z * y.z + y.w * y.w, 1e-6f, &mean, &rstd);
    float4 s4 = ((const float4*)psc)[t];
    float4 b4 = ((const float4*)pbi)[t];
    float4 nm = {(y.x - mean) * rstd * s4.x + b4.x,
                 (y.y - mean) * rstd * s4.y + b4.y,
                 (y.z - mean) * rstd * s4.z + b4.z,
                 (y.w - mean) * rstd * s4.w + b4.w};
    int mk = g_mask[b * 64 + s];
    float4 sel = mk ? nm : mv;
    ((float4*)(memOut + row * 1024))[t] = sel;
    float m2, rs2;
    block_stats(sel.x + sel.y + sel.z + sel.w,
                sel.x * sel.x + sel.y * sel.y + sel.z * sel.z + sel.w * sel.w,
                1e-6f, &m2, &rs2);
    float4 c4 = ((const float4*)qsc)[t];
    float4 d4 = ((const float4*)qbi)[t];
    f16x4 o;
    o[0] = (_Float16)((sel.x - m2) * rs2 * c4.x + d4.x);
    o[1] = (_Float16)((sel.y - m2) * rs2 * c4.y + d4.y);
    o[2] = (_Float16)((sel.z - m2) * rs2 * c4.z + d4.z);
    o[3] = (_Float16)((sel.w - m2) * rs2 * c4.w + d4.w);
    *(f16x4*)(g_hmem + row * 1024 + t * 4) = o;
}

// ---------------------------------------------------------------------------
extern "C" void kernel_launch(void* const* d_in, const int* in_sizes, int n_in,
                              void* d_out, int out_size, void* d_ws, size_t ws_size,
                              hipStream_t stream) {
    (void)in_sizes; (void)n_in; (void)d_ws; (void)ws_size; (void)out_size;
    const float* hidden    = (const float*)d_in[0];
    const unsigned int* mk = (const unsigned int*)d_in[1];
    const float* mem_state = (const float*)d_in[2];
    const float* wq  = (const float*)d_in[3];
    const float* wk  = (const float*)d_in[4];
    const float* wv  = (const float*)d_in[5];
    const float* wo  = (const float*)d_in[6];
    const float* pre_s  = (const float*)d_in[7];
    const float* pre_b  = (const float*)d_in[8];
    const float* post_s = (const float*)d_in[9];
    const float* post_b = (const float*)d_in[10];
    float* out = (float*)d_out;

    k_transpose<<<dim3(16, 16), 256, 0, stream>>>(wq, 1024, 0);
    k_transpose<<<dim3(16, 8),  256, 0, stream>>>(wk, 512, 1);
    k_transpose<<<dim3(16, 8),  256, 0, stream>>>(wv, 512, 2);
    k_transpose<<<dim3(16, 16), 256, 0, stream>>>(wo, 1024, 3);
    k_rope<<<1, 128, 0, stream>>>();
    k_mask<<<1, 1024, 0, stream>>>(mk);
    k_ln_hx<<<NB * NMs * MBs, 256, 0, stream>>>(hidden, pre_s, pre_b);
    k_ln_init<<<NB * MEMm, 256, 0, stream>>>(mem_state, pre_s, pre_b);
    k_kvx<<<dim3(512, 8), 256, 0, stream>>>();

    for (int s = 0; s < NMs; ++s) {
        k_step1<<<NB * NHh, 256, 0, stream>>>(s);
        k_gemm2<<<NB * NHh, 256, 0, stream>>>();
        k_ln2<<<NB * MEMm, 256, 0, stream>>>(s, out, post_s, post_b, pre_s, pre_b);
    }
}